// Round 13
// baseline (83.373 us; speedup 1.0000x reference)
//
#include <hip/hip_runtime.h>
#include <cstdint>
#include <cstddef>

typedef __attribute__((ext_vector_type(4))) short short4v;
typedef __attribute__((ext_vector_type(4))) float float4v;

#define C_IN  64
#define NB    2
#define NPTS  32768   // 32*32*32
#define MPTS  4096    // 16*16*16
#define LOG2E 1.44269504088896340736f
#define KT    64                // keys per staged tile
#define NTILE (MPTS / KT)       // 64
#define QT64  (NPTS / 64)       // 512 per batch

__device__ __forceinline__ unsigned short f2bf_rne(float f) {
  unsigned int u = __builtin_bit_cast(unsigned int, f);
  u += 0x7fffu + ((u >> 16) & 1u);
  return (unsigned short)(u >> 16);
}

__device__ __forceinline__ short4v pack_bf16_trunc(float a0, float a1, float a2, float a3) {
  unsigned int u0 = __builtin_amdgcn_perm(__builtin_bit_cast(unsigned int, a1),
                                          __builtin_bit_cast(unsigned int, a0), 0x07060302u);
  unsigned int u1 = __builtin_amdgcn_perm(__builtin_bit_cast(unsigned int, a3),
                                          __builtin_bit_cast(unsigned int, a2), 0x07060302u);
  union { unsigned int u[2]; short4v s; } r;
  r.u[0] = u0; r.u[1] = u1;
  return r.s;
}

__device__ __forceinline__ short4v pack_bf16_rne(float a0, float a1, float a2, float a3) {
  short4v s;
  s[0] = (short)f2bf_rne(a0); s[1] = (short)f2bf_rne(a1);
  s[2] = (short)f2bf_rne(a2); s[3] = (short)f2bf_rne(a3);
  return s;
}

__device__ __forceinline__ uint2 pack_bf16x4_u2(float4v a) {
  uint2 r;
  r.x = (unsigned int)f2bf_rne(a[0]) | ((unsigned int)f2bf_rne(a[1]) << 16);
  r.y = (unsigned int)f2bf_rne(a[2]) | ((unsigned int)f2bf_rne(a[3]) << 16);
  return r;
}

__device__ __forceinline__ void unpack2_add(unsigned int ux, unsigned int uy, float4v* a) {
  (*a)[0] += __builtin_bit_cast(float, ux << 16);
  (*a)[1] += __builtin_bit_cast(float, ux & 0xffff0000u);
  (*a)[2] += __builtin_bit_cast(float, uy << 16);
  (*a)[3] += __builtin_bit_cast(float, uy & 0xffff0000u);
}

__device__ __forceinline__ void gl_lds16(const unsigned short* g, unsigned short* l) {
  __builtin_amdgcn_global_load_lds(
      (const __attribute__((address_space(1))) void*)g,
      (__attribute__((address_space(3))) void*)l, 16, 0, 0);
}

// ---------------------------------------------------------------------------
// Fragment layouts (lane-major, 512B-contiguous per wave read, 0 conflicts):
// 16x16 bf16 MFMA A-fragment: element (row c, k) at pos ((k>>2)*16 + c)*4 + (k&3).
// phi_f: [B][256 frag][256]    (row = key, k = channel; log2e folded; ch 8..15 zero)
// g_f:   [B][256 frag][2][256] (row = channel within half, k = key)
// theta_pad: [B][N][16] bf16 (upper 8 ch zero) -> B-frag loads
// ---------------------------------------------------------------------------

// Pool: thread = (cg of 8 out-ch, b, m, half). Each thread computes 8 channels
// over 4 pooled positions (dd = half); one shfl_xor(1) merges the two halves.
// 5 cgroups x 2 halves -> x amplification 5x (84 MB, L3-resident), 320 blocks.
__device__ void pool_body(int idx, const float* __restrict__ x,
                          const float* __restrict__ w_phi,
                          const float* __restrict__ w_g,
                          unsigned short* __restrict__ phi_f,
                          unsigned short* __restrict__ g_f) {
  int cg = idx >> 14;            // 0..4
  int rem = idx & 16383;
  int bm = rem >> 1;             // b*4096 + m
  int half = rem & 1;            // dd of the 2x2x2 window
  int b = bm >> 12, m = bm & 4095;
  int md = m >> 8, mh = (m >> 4) & 15, mw = m & 15;
  const float* xb = x + (size_t)b * C_IN * NPTS
                  + ((md * 2 + half) * 1024 + (mh * 2) * 32 + (mw * 2));
  const float* wbase = (cg == 0) ? w_phi : (w_g + (cg - 1) * 8 * C_IN);

  float acc[8][4];
#pragma unroll
  for (int o = 0; o < 8; ++o)
#pragma unroll
    for (int p = 0; p < 4; ++p) acc[o][p] = 0.f;

#pragma unroll 4
  for (int cc = 0; cc < C_IN; ++cc) {
    const float* xp = xb + (size_t)cc * NPTS;
    float2 p01 = *(const float2*)(xp + 0);
    float2 p23 = *(const float2*)(xp + 32);
#pragma unroll
    for (int o = 0; o < 8; ++o) {
      float wv = wbase[o * C_IN + cc];
      acc[o][0] = fmaf(wv, p01.x, acc[o][0]);
      acc[o][1] = fmaf(wv, p01.y, acc[o][1]);
      acc[o][2] = fmaf(wv, p23.x, acc[o][2]);
      acc[o][3] = fmaf(wv, p23.y, acc[o][3]);
    }
  }
  float mx[8];
#pragma unroll
  for (int o = 0; o < 8; ++o) {
    float v = fmaxf(fmaxf(acc[o][0], acc[o][1]), fmaxf(acc[o][2], acc[o][3]));
    v = fmaxf(v, __shfl_xor(v, 1, 64));   // merge dd=0 / dd=1 halves
    mx[o] = v;
  }
  if (half != 0) return;

  int kt16 = m >> 4, kr = m & 15;
  if (cg == 0) {
    size_t fb = ((size_t)b * 256 + kt16) * 256;
#pragma unroll
    for (int g2 = 0; g2 < 2; ++g2) {
      unsigned int u0 = (unsigned int)f2bf_rne(mx[g2 * 4 + 0] * LOG2E)
                      | ((unsigned int)f2bf_rne(mx[g2 * 4 + 1] * LOG2E) << 16);
      unsigned int u1 = (unsigned int)f2bf_rne(mx[g2 * 4 + 2] * LOG2E)
                      | ((unsigned int)f2bf_rne(mx[g2 * 4 + 3] * LOG2E) << 16);
      *(uint2*)&phi_f[fb + (g2 * 16 + kr) * 4] = make_uint2(u0, u1);
      *(uint2*)&phi_f[fb + ((g2 + 2) * 16 + kr) * 4] = make_uint2(0u, 0u);  // zero ch 8..15
    }
  } else {
    int gc0 = (cg - 1) * 8;
#pragma unroll
    for (int o = 0; o < 8; ++o) {
      int c = gc0 + o;
      int halfc = c >> 4, c15 = c & 15;
      size_t base = (((size_t)b * 256 + kt16) * 2 + halfc) * 256;
      g_f[base + ((kr >> 2) * 16 + c15) * 4 + (kr & 3)] = f2bf_rne(mx[o]);
    }
  }
}

__device__ void theta_body(int idx, const float* __restrict__ x,
                           const float* __restrict__ w_theta,
                           unsigned short* __restrict__ theta_pad) {
  int b = idx >> 15, n = idx & 32767;
  const float* xb = x + (size_t)b * C_IN * NPTS + n;
  float t[8];
#pragma unroll
  for (int o = 0; o < 8; ++o) t[o] = 0.f;
#pragma unroll 4
  for (int cc = 0; cc < C_IN; ++cc) {
    float xv = xb[(size_t)cc * NPTS];
#pragma unroll
    for (int o = 0; o < 8; ++o) t[o] = fmaf(w_theta[o * C_IN + cc], xv, t[o]);
  }
  unsigned int w0 = (unsigned int)f2bf_rne(t[0]) | ((unsigned int)f2bf_rne(t[1]) << 16);
  unsigned int w1 = (unsigned int)f2bf_rne(t[2]) | ((unsigned int)f2bf_rne(t[3]) << 16);
  unsigned int w2 = (unsigned int)f2bf_rne(t[4]) | ((unsigned int)f2bf_rne(t[5]) << 16);
  unsigned int w3 = (unsigned int)f2bf_rne(t[6]) | ((unsigned int)f2bf_rne(t[7]) << 16);
  uint4* dst = (uint4*)(theta_pad + ((size_t)idx << 4));
  dst[0] = make_uint4(w0, w1, w2, w3);
  dst[1] = make_uint4(0u, 0u, 0u, 0u);
}

__global__ __launch_bounds__(256) void prep_fused(
    const float* __restrict__ x, const float* __restrict__ w_theta,
    const float* __restrict__ w_phi, const float* __restrict__ w_g,
    unsigned short* __restrict__ theta_pad,
    unsigned short* __restrict__ phi_f,
    unsigned short* __restrict__ g_f) {
  int gb = blockIdx.x;
  if (gb < 320) {
    pool_body(gb * 256 + threadIdx.x, x, w_phi, w_g, phi_f, g_f);
  } else {
    theta_body((gb - 320) * 256 + threadIdx.x, x, w_theta, theta_pad);
  }
}

// ---------------------------------------------------------------------------
// Pass 1: split-K flash attention, 64 queries/wave, KT=64 tiles, bf16 partial
// output (uint4-packed: 2 accs / 16B). 3-buffer LDS pipeline with counted
// vmcnt (r12-proven). Grid (NPTS/256, NB*KS), block 256.
// opart: [B*KS][QT64][4 slots(h*2+jp)][64 lanes] uint4; lbuf f32.
// ---------------------------------------------------------------------------
template <int KS>
__global__ __launch_bounds__(256, 4) void attn_split64(
    const unsigned short* __restrict__ theta_pad,
    const unsigned short* __restrict__ phi_f,
    const unsigned short* __restrict__ g_f,
    uint4* __restrict__ opart,
    float* __restrict__ lbuf) {
  __shared__ unsigned short s_phi[3][KT * 16];       // 3 x 2 KB
  __shared__ unsigned short s_g[3][(KT / 16) * 512]; // 3 x 4 KB

  int tid = threadIdx.x;
  int wid = tid >> 6, lane = tid & 63;
  int l4 = lane >> 4, col = lane & 15;
  int b = blockIdx.y / KS;
  int ks = blockIdx.y % KS;
  int qb = blockIdx.x * 256 + wid * 64;
  int qt64 = blockIdx.x * 4 + wid;
  int t0 = ks * (NTILE / KS);
  const int T = NTILE / KS;

  // 4 theta B-frags (64 queries)
  const unsigned short* tb = theta_pad + ((size_t)(b * NPTS + qb) << 4) + l4 * 4;
  short4v bt0 = *(const short4v*)(tb + ((0 * 16 + col) << 4));
  short4v bt1 = *(const short4v*)(tb + ((1 * 16 + col) << 4));
  short4v bt2 = *(const short4v*)(tb + ((2 * 16 + col) << 4));
  short4v bt3 = *(const short4v*)(tb + ((3 * 16 + col) << 4));

  const unsigned short* phib = phi_f + (size_t)b * 65536;
  const unsigned short* gb   = g_f + (size_t)b * 131072;

  float4v acc[2][4];
#pragma unroll
  for (int h = 0; h < 2; ++h)
#pragma unroll
    for (int j = 0; j < 4; ++j) acc[h][j] = (float4v){0.f, 0.f, 0.f, 0.f};
  float lsum0 = 0.f, lsum1 = 0.f, lsum2 = 0.f, lsum3 = 0.f;

  // uniform staging: every thread issues exactly 2 global_load_lds (1 g, 1 phi;
  // waves 2,3 duplicate phi halves of waves 0,1 -> benign same-data writes).
#define STAGE(tt, bb)                                                          \
  do {                                                                         \
    gl_lds16(gb + (size_t)(tt) * 2048 + wid * 512 + lane * 8,                  \
             &s_g[bb][wid * 512]);                                             \
    gl_lds16(phib + (size_t)(tt) * 1024 + (wid & 1) * 512 + lane * 8,          \
             &s_phi[bb][(wid & 1) * 512]);                                     \
  } while (0)

  // prologue: tiles t0 -> buf0, t0+1 -> buf1 (4 loads outstanding/thread)
  STAGE(t0, 0);
  STAGE(t0 + 1, 1);

  int cur = 0;
#pragma unroll 1
  for (int i = 0; i < T; ++i) {
    if (i + 1 < T) {
      asm volatile("s_waitcnt vmcnt(2)" ::: "memory");   // own tile-i loads done
    } else {
      asm volatile("s_waitcnt vmcnt(0)" ::: "memory");
    }
    __builtin_amdgcn_s_barrier();                        // all waves' tile-i done
    __builtin_amdgcn_sched_barrier(0);

#pragma unroll
    for (int st = 0; st < 4; ++st) {
      short4v pf = *(const short4v*)&s_phi[cur][st * 256 + lane * 4];
      short4v g0 = *(const short4v*)&s_g[cur][st * 512 + lane * 4];
      short4v g1 = *(const short4v*)&s_g[cur][st * 512 + 256 + lane * 4];

      float4v zero4 = {0.f, 0.f, 0.f, 0.f};
      float4v s0 = __builtin_amdgcn_mfma_f32_16x16x16bf16_1k(pf, bt0, zero4, 0, 0, 0);
      float4v s1 = __builtin_amdgcn_mfma_f32_16x16x16bf16_1k(pf, bt1, zero4, 0, 0, 0);
      float4v s2 = __builtin_amdgcn_mfma_f32_16x16x16bf16_1k(pf, bt2, zero4, 0, 0, 0);
      float4v s3 = __builtin_amdgcn_mfma_f32_16x16x16bf16_1k(pf, bt3, zero4, 0, 0, 0);

      float p00 = __builtin_amdgcn_exp2f(s0[0]);
      float p01 = __builtin_amdgcn_exp2f(s0[1]);
      float p02 = __builtin_amdgcn_exp2f(s0[2]);
      float p03 = __builtin_amdgcn_exp2f(s0[3]);
      float p10 = __builtin_amdgcn_exp2f(s1[0]);
      float p11 = __builtin_amdgcn_exp2f(s1[1]);
      float p12 = __builtin_amdgcn_exp2f(s1[2]);
      float p13 = __builtin_amdgcn_exp2f(s1[3]);
      float p20 = __builtin_amdgcn_exp2f(s2[0]);
      float p21 = __builtin_amdgcn_exp2f(s2[1]);
      float p22 = __builtin_amdgcn_exp2f(s2[2]);
      float p23 = __builtin_amdgcn_exp2f(s2[3]);
      float p30 = __builtin_amdgcn_exp2f(s3[0]);
      float p31 = __builtin_amdgcn_exp2f(s3[1]);
      float p32 = __builtin_amdgcn_exp2f(s3[2]);
      float p33 = __builtin_amdgcn_exp2f(s3[3]);
      lsum0 += (p00 + p01) + (p02 + p03);
      lsum1 += (p10 + p11) + (p12 + p13);
      lsum2 += (p20 + p21) + (p22 + p23);
      lsum3 += (p30 + p31) + (p32 + p33);
      short4v pb0 = pack_bf16_trunc(p00, p01, p02, p03);
      short4v pb1 = pack_bf16_trunc(p10, p11, p12, p13);
      short4v pb2 = pack_bf16_trunc(p20, p21, p22, p23);
      short4v pb3 = pack_bf16_trunc(p30, p31, p32, p33);

      acc[0][0] = __builtin_amdgcn_mfma_f32_16x16x16bf16_1k(g0, pb0, acc[0][0], 0, 0, 0);
      acc[0][1] = __builtin_amdgcn_mfma_f32_16x16x16bf16_1k(g0, pb1, acc[0][1], 0, 0, 0);
      acc[0][2] = __builtin_amdgcn_mfma_f32_16x16x16bf16_1k(g0, pb2, acc[0][2], 0, 0, 0);
      acc[0][3] = __builtin_amdgcn_mfma_f32_16x16x16bf16_1k(g0, pb3, acc[0][3], 0, 0, 0);
      acc[1][0] = __builtin_amdgcn_mfma_f32_16x16x16bf16_1k(g1, pb0, acc[1][0], 0, 0, 0);
      acc[1][1] = __builtin_amdgcn_mfma_f32_16x16x16bf16_1k(g1, pb1, acc[1][1], 0, 0, 0);
      acc[1][2] = __builtin_amdgcn_mfma_f32_16x16x16bf16_1k(g1, pb2, acc[1][2], 0, 0, 0);
      acc[1][3] = __builtin_amdgcn_mfma_f32_16x16x16bf16_1k(g1, pb3, acc[1][3], 0, 0, 0);
    }

    // stage tile i+2 into buffer (cur+2)%3 — its last readers (tile i-1)
    // all passed this iteration's barrier.
    if (i + 2 < T) {
      int bb = (cur + 2 >= 3) ? cur - 1 : cur + 2;
      STAGE(t0 + i + 2, bb);
    }
    cur = (cur == 2) ? 0 : cur + 1;
  }
#undef STAGE

  lsum0 += __shfl_xor(lsum0, 16, 64);
  lsum0 += __shfl_xor(lsum0, 32, 64);
  lsum1 += __shfl_xor(lsum1, 16, 64);
  lsum1 += __shfl_xor(lsum1, 32, 64);
  lsum2 += __shfl_xor(lsum2, 16, 64);
  lsum2 += __shfl_xor(lsum2, 32, 64);
  lsum3 += __shfl_xor(lsum3, 16, 64);
  lsum3 += __shfl_xor(lsum3, 32, 64);

  size_t rowb = (size_t)(b * KS + ks) * QT64 + qt64;
  float myl = (l4 == 0) ? lsum0 : (l4 == 1) ? lsum1 : (l4 == 2) ? lsum2 : lsum3;
  lbuf[rowb * 64 + lane] = myl;   // entry q = l4*16+col

  // uint4 slot (h*2+jp) holds accs (h, 2jp) and (h, 2jp+1)
  size_t obase = rowb * 4 * 64 + lane;
#pragma unroll
  for (int h = 0; h < 2; ++h)
#pragma unroll
    for (int jp = 0; jp < 2; ++jp) {
      uint2 lo = pack_bf16x4_u2(acc[h][jp * 2]);
      uint2 hi = pack_bf16x4_u2(acc[h][jp * 2 + 1]);
      opart[obase + (size_t)(h * 2 + jp) * 64] = make_uint4(lo.x, lo.y, hi.x, hi.y);
    }
}

// ---------------------------------------------------------------------------
// Pass 2: combine bf16 partials (uint4 loads), normalize, w_o epilogue MFMA,
// gamma, residual. Wave handles 32 queries. Grid (NPTS/128, NB).
// ---------------------------------------------------------------------------
template <int KS>
__global__ __launch_bounds__(256) void attn_combine(
    const float* __restrict__ x, const float* __restrict__ w_o,
    const float* __restrict__ gamma_p,
    const uint4* __restrict__ opart,
    const float* __restrict__ lbuf,
    float* __restrict__ out) {
  int tid = threadIdx.x;
  int wid = tid >> 6, lane = tid & 63;
  int l4 = lane >> 4, col = lane & 15;
  int b = blockIdx.y;
  int qt32 = blockIdx.x * 4 + wid;
  int qb = qt32 * 32;
  int qt64 = qt32 >> 1, hf = qt32 & 1;

  float gamma = gamma_p[0];

  short4v wo[4][2];
#pragma unroll
  for (int cot = 0; cot < 4; ++cot)
#pragma unroll
    for (int ksw = 0; ksw < 2; ++ksw) {
      const float* wp = w_o + (cot * 16 + col) * 32 + ksw * 16 + l4 * 4;
      wo[cot][ksw] = pack_bf16_rne(wp[0] * gamma, wp[1] * gamma,
                                   wp[2] * gamma, wp[3] * gamma);
    }

  float4v a0 = {0.f, 0.f, 0.f, 0.f}, a1 = a0, a2 = a0, a3 = a0;
  float ls0 = 0.f, ls1 = 0.f;
#pragma unroll
  for (int ks = 0; ks < KS; ++ks) {
    size_t rowb = (size_t)(b * KS + ks) * QT64 + qt64;
    size_t ob = (rowb * 4 + hf) * 64 + lane;
    uint4 u01 = opart[ob];            // h=0: accs (0,2hf),(0,2hf+1)
    uint4 u23 = opart[ob + 2 * 64];   // h=1: accs (1,2hf),(1,2hf+1)
    unpack2_add(u01.x, u01.y, &a0);
    unpack2_add(u01.z, u01.w, &a1);
    unpack2_add(u23.x, u23.y, &a2);
    unpack2_add(u23.z, u23.w, &a3);
    const float* lb = lbuf + rowb * 64 + hf * 32;
    ls0 += lb[col];
    ls1 += lb[col + 16];
  }
  float li0 = 1.0f / ls0;
  float li1 = 1.0f / ls1;

  short4v onb00 = pack_bf16_rne(a0[0] * li0, a0[1] * li0, a0[2] * li0, a0[3] * li0);
  short4v onb01 = pack_bf16_rne(a1[0] * li1, a1[1] * li1, a1[2] * li1, a1[3] * li1);
  short4v onb10 = pack_bf16_rne(a2[0] * li0, a2[1] * li0, a2[2] * li0, a2[3] * li0);
  short4v onb11 = pack_bf16_rne(a3[0] * li1, a3[1] * li1, a3[2] * li1, a3[3] * li1);

  float4v zero4 = {0.f, 0.f, 0.f, 0.f};
#pragma unroll
  for (int cot = 0; cot < 4; ++cot) {
#pragma unroll
    for (int nt = 0; nt < 2; ++nt) {
      short4v bfrag0 = nt ? onb01 : onb00;
      short4v bfrag1 = nt ? onb11 : onb10;
      float4v d = __builtin_amdgcn_mfma_f32_16x16x16bf16_1k(wo[cot][0], bfrag0, zero4, 0, 0, 0);
      d = __builtin_amdgcn_mfma_f32_16x16x16bf16_1k(wo[cot][1], bfrag1, d, 0, 0, 0);
      int n = qb + nt * 16 + col;
      size_t base = (size_t)(b * C_IN + cot * 16 + l4 * 4) * NPTS + n;
      const float* xp = x + base;
      float* op = out + base;
#pragma unroll
      for (int e = 0; e < 4; ++e) {
        op[(size_t)e * NPTS] = d[e] + xp[(size_t)e * NPTS];
      }
    }
  }
}

// ---------------------------------------------------------------------------
// Fallback single-pass attention (r5-proven) for small ws_size.
// ---------------------------------------------------------------------------
__global__ __launch_bounds__(256) void attn_mfma(
    const float* __restrict__ x, const float* __restrict__ w_o,
    const float* __restrict__ gamma_p,
    const unsigned short* __restrict__ theta_pad,
    const unsigned short* __restrict__ phi_f,
    const unsigned short* __restrict__ g_f,
    float* __restrict__ out) {
  __shared__ unsigned short s_phi[2][KT * 16];
  __shared__ unsigned short s_g[2][(KT / 16) * 512];

  int tid = threadIdx.x;
  int wid = tid >> 6, lane = tid & 63;
  int l4 = lane >> 4, col = lane & 15;
  int b = blockIdx.y;
  int qb = blockIdx.x * 128 + wid * 32;

  float gamma = gamma_p[0];

  const unsigned short* tb = theta_pad + ((size_t)(b * NPTS + qb) << 4) + l4 * 4;
  short4v bt0 = *(const short4v*)(tb + (col << 4));
  short4v bt1 = *(const short4v*)(tb + ((16 + col) << 4));

  short4v wo[4][2];
#pragma unroll
  for (int cot = 0; cot < 4; ++cot)
#pragma unroll
    for (int ksw = 0; ksw < 2; ++ksw) {
      const float* wp = w_o + (cot * 16 + col) * 32 + ksw * 16 + l4 * 4;
      wo[cot][ksw] = pack_bf16_rne(wp[0] * gamma, wp[1] * gamma,
                                   wp[2] * gamma, wp[3] * gamma);
    }

  const unsigned short* phib = phi_f + (size_t)b * 256 * 256;
  const unsigned short* gb   = g_f + (size_t)b * 256 * 512;

  float4v acc00 = {0.f, 0.f, 0.f, 0.f}, acc01 = acc00, acc10 = acc00, acc11 = acc00;
  float lsum0 = 0.f, lsum1 = 0.f;

  gl_lds16(gb + 0 * 2048 + wid * 512 + lane * 8, &s_g[0][wid * 512]);
  if (wid < 2)
    gl_lds16(phib + 0 * 1024 + wid * 512 + lane * 8, &s_phi[0][wid * 512]);
  __syncthreads();

#pragma unroll 1
  for (int t = 0; t < NTILE; ++t) {
    int cur = t & 1;
    if (t + 1 < NTILE) {
      gl_lds16(gb + (size_t)(t + 1) * 2048 + wid * 512 + lane * 8,
               &s_g[cur ^ 1][wid * 512]);
      if (wid < 2)
        gl_lds16(phib + (size_t)(t + 1) * 1024 + wid * 512 + lane * 8,
                 &s_phi[cur ^ 1][wid * 512]);
    }
#pragma unroll
    for (int st = 0; st < 4; ++st) {
      short4v pf = *(const short4v*)&s_phi[cur][st * 256 + lane * 4];
      short4v g0 = *(const short4v*)&s_g[cur][st * 512 + lane * 4];
      short4v g1 = *(const short4v*)&s_g[cur][st * 512 + 256 + lane * 4];

      float4v zero4 = {0.f, 0.f, 0.f, 0.f};
      float4v s0 = __builtin_amdgcn_mfma_f32_16x16x16bf16_1k(pf, bt0, zero4, 0, 0, 0);
      float4v s1 = __builtin_amdgcn_mfma_f32_16x16x16bf16_1k(pf, bt1, zero4, 0, 0, 0);

      float p00 = __builtin_amdgcn_exp2f(s0[0]);
      float p01 = __builtin_amdgcn_exp2f(s0[1]);
      float p02 = __builtin_amdgcn_exp2f(s0[2]);
      float p03 = __builtin_amdgcn_exp2f(s0[3]);
      float p10 = __builtin_amdgcn_exp2f(s1[0]);
      float p11 = __builtin_amdgcn_exp2f(s1[1]);
      float p12 = __builtin_amdgcn_exp2f(s1[2]);
      float p13 = __builtin_amdgcn_exp2f(s1[3]);
      lsum0 += (p00 + p01) + (p02 + p03);
      lsum1 += (p10 + p11) + (p12 + p13);
      short4v pb0 = pack_bf16_trunc(p00, p01, p02, p03);
      short4v pb1 = pack_bf16_trunc(p10, p11, p12, p13);

      acc00 = __builtin_amdgcn_mfma_f32_16x16x16bf16_1k(g0, pb0, acc00, 0, 0, 0);
      acc01 = __builtin_amdgcn_mfma_f32_16x16x16bf16_1k(g0, pb1, acc01, 0, 0, 0);
      acc10 = __builtin_amdgcn_mfma_f32_16x16x16bf16_1k(g1, pb0, acc10, 0, 0, 0);
      acc11 = __builtin_amdgcn_mfma_f32_16x16x16bf16_1k(g1, pb1, acc11, 0, 0, 0);
    }
    __syncthreads();
  }

  lsum0 += __shfl_xor(lsum0, 16, 64);
  lsum0 += __shfl_xor(lsum0, 32, 64);
  lsum1 += __shfl_xor(lsum1, 16, 64);
  lsum1 += __shfl_xor(lsum1, 32, 64);
  float li0 = 1.0f / lsum0;
  float li1 = 1.0f / lsum1;

  short4v onb00 = pack_bf16_rne(acc00[0] * li0, acc00[1] * li0, acc00[2] * li0, acc00[3] * li0);
  short4v onb01 = pack_bf16_rne(acc01[0] * li1, acc01[1] * li1, acc01[2] * li1, acc01[3] * li1);
  short4v onb10 = pack_bf16_rne(acc10[0] * li0, acc10[1] * li0, acc10[2] * li0, acc10[3] * li0);
  short4v onb11 = pack_bf16_rne(acc11[0] * li1, acc11[1] * li1, acc11[2] * li1, acc11[3] * li1);

  float4v zero4 = {0.f, 0.f, 0.f, 0.f};
#pragma unroll
  for (int cot = 0; cot < 4; ++cot) {
#pragma unroll
    for (int nt = 0; nt < 2; ++nt) {
      short4v bfrag0 = nt ? onb01 : onb00;
      short4v bfrag1 = nt ? onb11 : onb10;
      float4v d = __builtin_amdgcn_mfma_f32_16x16x16bf16_1k(wo[cot][0], bfrag0, zero4, 0, 0, 0);
      d = __builtin_amdgcn_mfma_f32_16x16x16bf16_1k(wo[cot][1], bfrag1, d, 0, 0, 0);
      int n = qb + nt * 16 + col;
      size_t base = (size_t)(b * C_IN + cot * 16 + l4 * 4) * NPTS + n;
      const float* xp = x + base;
      float* op = out + base;
#pragma unroll
      for (int e = 0; e < 4; ++e) {
        op[(size_t)e * NPTS] = d[e] + xp[(size_t)e * NPTS];
      }
    }
  }
}

extern "C" void kernel_launch(void* const* d_in, const int* in_sizes, int n_in,
                              void* d_out, int out_size, void* d_ws, size_t ws_size,
                              hipStream_t stream) {
  const float* x       = (const float*)d_in[0];
  const float* w_theta = (const float*)d_in[1];
  const float* w_phi   = (const float*)d_in[2];
  const float* w_g     = (const float*)d_in[3];
  const float* w_o     = (const float*)d_in[4];
  const float* gamma   = (const float*)d_in[5];
  float* out = (float*)d_out;

  char* ws = (char*)d_ws;
  unsigned short* phi_f     = (unsigned short*)ws;  ws += (size_t)NB * 256 * 256 * 2;  // 256 KB
  unsigned short* g_f       = (unsigned short*)ws;  ws += (size_t)NB * 256 * 512 * 2;  // 512 KB
  unsigned short* theta_pad = (unsigned short*)ws;  ws += (size_t)NB * NPTS * 16 * 2;  // 2 MB
  size_t base_need = (size_t)(ws - (char*)d_ws);
  uint4* opart = (uint4*)ws;
  size_t opart4 = (size_t)NB * 4 * QT64 * 4 * 64 * sizeof(uint4);    // 16.8 MB
  size_t opart2 = (size_t)NB * 2 * QT64 * 4 * 64 * sizeof(uint4);    // 8.4 MB
  size_t lbuf4  = (size_t)NB * 4 * QT64 * 64 * sizeof(float);        // 1 MB
  size_t lbuf2  = (size_t)NB * 2 * QT64 * 64 * sizeof(float);
  size_t need4 = base_need + opart4 + lbuf4;
  size_t need2 = base_need + opart2 + lbuf2;

  prep_fused<<<dim3(576), dim3(256), 0, stream>>>(
      x, w_theta, w_phi, w_g, theta_pad, phi_f, g_f);

  if (ws_size >= need4) {
    float* lbuf = (float*)((char*)opart + opart4);
    attn_split64<4><<<dim3(NPTS / 256, NB * 4), dim3(256), 0, stream>>>(
        theta_pad, phi_f, g_f, opart, lbuf);
    attn_combine<4><<<dim3(NPTS / 128, NB), dim3(256), 0, stream>>>(
        x, w_o, gamma, opart, lbuf, out);
  } else if (ws_size >= need2) {
    float* lbuf = (float*)((char*)opart + opart2);
    attn_split64<2><<<dim3(NPTS / 256, NB * 2), dim3(256), 0, stream>>>(
        theta_pad, phi_f, g_f, opart, lbuf);
    attn_combine<2><<<dim3(NPTS / 128, NB), dim3(256), 0, stream>>>(
        x, w_o, gamma, opart, lbuf, out);
  } else if (ws_size >= base_need) {
    attn_mfma<<<dim3(NPTS / 128, NB), dim3(256), 0, stream>>>(
        x, w_o, gamma, theta_pad, phi_f, g_f, out);
  }
}

// Round 14
// 78.923 us; speedup vs baseline: 1.0564x; 1.0564x over previous
//
#include <hip/hip_runtime.h>
#include <cstdint>
#include <cstddef>

typedef __attribute__((ext_vector_type(4))) short short4v;
typedef __attribute__((ext_vector_type(4))) float float4v;

#define C_IN  64
#define NB    2
#define NPTS  32768   // 32*32*32
#define MPTS  4096    // 16*16*16
#define LOG2E 1.44269504088896340736f
#define KT    64                // keys per staged tile
#define NTILE (MPTS / KT)       // 64
#define QT64  (NPTS / 64)       // 512 per batch

__device__ __forceinline__ unsigned short f2bf_rne(float f) {
  unsigned int u = __builtin_bit_cast(unsigned int, f);
  u += 0x7fffu + ((u >> 16) & 1u);
  return (unsigned short)(u >> 16);
}

__device__ __forceinline__ short4v pack_bf16_trunc(float a0, float a1, float a2, float a3) {
  unsigned int u0 = __builtin_amdgcn_perm(__builtin_bit_cast(unsigned int, a1),
                                          __builtin_bit_cast(unsigned int, a0), 0x07060302u);
  unsigned int u1 = __builtin_amdgcn_perm(__builtin_bit_cast(unsigned int, a3),
                                          __builtin_bit_cast(unsigned int, a2), 0x07060302u);
  union { unsigned int u[2]; short4v s; } r;
  r.u[0] = u0; r.u[1] = u1;
  return r.s;
}

__device__ __forceinline__ short4v pack_bf16_rne(float a0, float a1, float a2, float a3) {
  short4v s;
  s[0] = (short)f2bf_rne(a0); s[1] = (short)f2bf_rne(a1);
  s[2] = (short)f2bf_rne(a2); s[3] = (short)f2bf_rne(a3);
  return s;
}

__device__ __forceinline__ uint2 pack_bf16x4_u2(float4v a) {
  uint2 r;
  r.x = (unsigned int)f2bf_rne(a[0]) | ((unsigned int)f2bf_rne(a[1]) << 16);
  r.y = (unsigned int)f2bf_rne(a[2]) | ((unsigned int)f2bf_rne(a[3]) << 16);
  return r;
}

__device__ __forceinline__ void unpack_bf16x4_add(uint2 u, float4v* a) {
  (*a)[0] += __builtin_bit_cast(float, u.x << 16);
  (*a)[1] += __builtin_bit_cast(float, u.x & 0xffff0000u);
  (*a)[2] += __builtin_bit_cast(float, u.y << 16);
  (*a)[3] += __builtin_bit_cast(float, u.y & 0xffff0000u);
}

__device__ __forceinline__ void gl_lds16(const unsigned short* g, unsigned short* l) {
  __builtin_amdgcn_global_load_lds(
      (const __attribute__((address_space(1))) void*)g,
      (__attribute__((address_space(3))) void*)l, 16, 0, 0);
}

// ---------------------------------------------------------------------------
// Fragment layouts (lane-major, 512B-contiguous per wave read, 0 conflicts):
// 16x16 bf16 MFMA A-fragment: element (row c, k) at pos ((k>>2)*16 + c)*4 + (k&3).
// phi_f: [B][256 frag][256]    (row = key, k = channel; log2e folded; ch 8..15 zero)
// g_f:   [B][256 frag][2][256] (row = channel within half, k = key)
// theta_pad: [B][N][16] bf16 (upper 8 ch zero) -> B-frag loads
// ---------------------------------------------------------------------------

__device__ void pool_body(int idx, const float* __restrict__ x,
                          const float* __restrict__ w_phi,
                          const float* __restrict__ w_g,
                          unsigned short* __restrict__ phi_f,
                          unsigned short* __restrict__ g_f) {
  int cg = idx >> 13;          // 0..9
  int bm = idx & 8191;
  int b = bm >> 12, m = bm & 4095;
  int md = m >> 8, mh = (m >> 4) & 15, mw = m & 15;
  const float* xb = x + (size_t)b * C_IN * NPTS
                  + ((md * 2) * 1024 + (mh * 2) * 32 + (mw * 2));
  const float* wbase = (cg < 2) ? (w_phi + cg * 4 * C_IN)
                                : (w_g + (cg - 2) * 4 * C_IN);

  float acc[4][8];
#pragma unroll
  for (int o = 0; o < 4; ++o)
#pragma unroll
    for (int p = 0; p < 8; ++p) acc[o][p] = 0.f;

#pragma unroll 4
  for (int cc = 0; cc < C_IN; ++cc) {
    const float* xp = xb + (size_t)cc * NPTS;
    float2 p01 = *(const float2*)(xp + 0);
    float2 p23 = *(const float2*)(xp + 32);
    float2 p45 = *(const float2*)(xp + 1024);
    float2 p67 = *(const float2*)(xp + 1056);
#pragma unroll
    for (int o = 0; o < 4; ++o) {
      float wv = wbase[o * C_IN + cc];
      acc[o][0] = fmaf(wv, p01.x, acc[o][0]);
      acc[o][1] = fmaf(wv, p01.y, acc[o][1]);
      acc[o][2] = fmaf(wv, p23.x, acc[o][2]);
      acc[o][3] = fmaf(wv, p23.y, acc[o][3]);
      acc[o][4] = fmaf(wv, p45.x, acc[o][4]);
      acc[o][5] = fmaf(wv, p45.y, acc[o][5]);
      acc[o][6] = fmaf(wv, p67.x, acc[o][6]);
      acc[o][7] = fmaf(wv, p67.y, acc[o][7]);
    }
  }
  float mx[4];
#pragma unroll
  for (int o = 0; o < 4; ++o) {
    mx[o] = fmaxf(fmaxf(fmaxf(acc[o][0], acc[o][1]), fmaxf(acc[o][2], acc[o][3])),
                  fmaxf(fmaxf(acc[o][4], acc[o][5]), fmaxf(acc[o][6], acc[o][7])));
  }
  int kt16 = m >> 4, kr = m & 15;
  if (cg < 2) {
    size_t fb = ((size_t)b * 256 + kt16) * 256;
    unsigned int u0 = (unsigned int)f2bf_rne(mx[0] * LOG2E)
                    | ((unsigned int)f2bf_rne(mx[1] * LOG2E) << 16);
    unsigned int u1 = (unsigned int)f2bf_rne(mx[2] * LOG2E)
                    | ((unsigned int)f2bf_rne(mx[3] * LOG2E) << 16);
    *(uint2*)&phi_f[fb + (cg * 16 + kr) * 4] = make_uint2(u0, u1);
    *(uint2*)&phi_f[fb + ((cg + 2) * 16 + kr) * 4] = make_uint2(0u, 0u);   // zero ch 8..15
  } else {
    int gc0 = (cg - 2) * 4;
#pragma unroll
    for (int o = 0; o < 4; ++o) {
      int c = gc0 + o;
      int half = c >> 4, c15 = c & 15;
      size_t base = (((size_t)b * 256 + kt16) * 2 + half) * 256;
      g_f[base + ((kr >> 2) * 16 + c15) * 4 + (kr & 3)] = f2bf_rne(mx[o]);
    }
  }
}

__device__ void theta_body(int idx, const float* __restrict__ x,
                           const float* __restrict__ w_theta,
                           unsigned short* __restrict__ theta_pad) {
  int b = idx >> 15, n = idx & 32767;
  const float* xb = x + (size_t)b * C_IN * NPTS + n;
  float t[8];
#pragma unroll
  for (int o = 0; o < 8; ++o) t[o] = 0.f;
#pragma unroll 4
  for (int cc = 0; cc < C_IN; ++cc) {
    float xv = xb[(size_t)cc * NPTS];
#pragma unroll
    for (int o = 0; o < 8; ++o) t[o] = fmaf(w_theta[o * C_IN + cc], xv, t[o]);
  }
  unsigned int w0 = (unsigned int)f2bf_rne(t[0]) | ((unsigned int)f2bf_rne(t[1]) << 16);
  unsigned int w1 = (unsigned int)f2bf_rne(t[2]) | ((unsigned int)f2bf_rne(t[3]) << 16);
  unsigned int w2 = (unsigned int)f2bf_rne(t[4]) | ((unsigned int)f2bf_rne(t[5]) << 16);
  unsigned int w3 = (unsigned int)f2bf_rne(t[6]) | ((unsigned int)f2bf_rne(t[7]) << 16);
  uint4* dst = (uint4*)(theta_pad + ((size_t)idx << 4));
  dst[0] = make_uint4(w0, w1, w2, w3);
  dst[1] = make_uint4(0u, 0u, 0u, 0u);
}

__global__ __launch_bounds__(256) void prep_fused(
    const float* __restrict__ x, const float* __restrict__ w_theta,
    const float* __restrict__ w_phi, const float* __restrict__ w_g,
    unsigned short* __restrict__ theta_pad,
    unsigned short* __restrict__ phi_f,
    unsigned short* __restrict__ g_f) {
  int gb = blockIdx.x;
  if (gb < 320) {
    pool_body(gb * 256 + threadIdx.x, x, w_phi, w_g, phi_f, g_f);
  } else {
    theta_body((gb - 320) * 256 + threadIdx.x, x, w_theta, theta_pad);
  }
}

// ---------------------------------------------------------------------------
// Pass 1: split-K flash attention, 64 queries/wave, KT=64 tiles, bf16 partial
// output. 3-buffer LDS pipeline with COUNTED vmcnt (T4): loads for tile t+1
// stay in flight across the barrier; each wave waits only its own tile-t
// loads (vmcnt(2), uniform 2 loads/thread/stage) BEFORE s_barrier, so after
// the barrier all waves' tile-t staging is complete.
// Grid (NPTS/256, NB*KS), block 256. opart bf16; lbuf f32.
// ---------------------------------------------------------------------------
template <int KS>
__global__ __launch_bounds__(256, 4) void attn_split64(
    const unsigned short* __restrict__ theta_pad,
    const unsigned short* __restrict__ phi_f,
    const unsigned short* __restrict__ g_f,
    uint2* __restrict__ opart,
    float* __restrict__ lbuf) {
  __shared__ unsigned short s_phi[3][KT * 16];       // 3 x 2 KB
  __shared__ unsigned short s_g[3][(KT / 16) * 512]; // 3 x 4 KB

  int tid = threadIdx.x;
  int wid = tid >> 6, lane = tid & 63;
  int l4 = lane >> 4, col = lane & 15;
  int b = blockIdx.y / KS;
  int ks = blockIdx.y % KS;
  int qb = blockIdx.x * 256 + wid * 64;
  int qt64 = blockIdx.x * 4 + wid;
  int t0 = ks * (NTILE / KS);
  const int T = NTILE / KS;

  // 4 theta B-frags (64 queries)
  const unsigned short* tb = theta_pad + ((size_t)(b * NPTS + qb) << 4) + l4 * 4;
  short4v bt0 = *(const short4v*)(tb + ((0 * 16 + col) << 4));
  short4v bt1 = *(const short4v*)(tb + ((1 * 16 + col) << 4));
  short4v bt2 = *(const short4v*)(tb + ((2 * 16 + col) << 4));
  short4v bt3 = *(const short4v*)(tb + ((3 * 16 + col) << 4));

  const unsigned short* phib = phi_f + (size_t)b * 65536;
  const unsigned short* gb   = g_f + (size_t)b * 131072;

  float4v acc[2][4];
#pragma unroll
  for (int h = 0; h < 2; ++h)
#pragma unroll
    for (int j = 0; j < 4; ++j) acc[h][j] = (float4v){0.f, 0.f, 0.f, 0.f};
  float lsum0 = 0.f, lsum1 = 0.f, lsum2 = 0.f, lsum3 = 0.f;

  // uniform staging: every thread issues exactly 2 global_load_lds (1 g, 1 phi;
  // waves 2,3 duplicate phi halves of waves 0,1 -> benign same-data writes).
#define STAGE(tt, bb)                                                          \
  do {                                                                         \
    gl_lds16(gb + (size_t)(tt) * 2048 + wid * 512 + lane * 8,                  \
             &s_g[bb][wid * 512]);                                             \
    gl_lds16(phib + (size_t)(tt) * 1024 + (wid & 1) * 512 + lane * 8,          \
             &s_phi[bb][(wid & 1) * 512]);                                     \
  } while (0)

  // prologue: tiles t0 -> buf0, t0+1 -> buf1 (4 loads outstanding/thread)
  STAGE(t0, 0);
  STAGE(t0 + 1, 1);

  int cur = 0;
#pragma unroll 1
  for (int i = 0; i < T; ++i) {
    if (i + 1 < T) {
      asm volatile("s_waitcnt vmcnt(2)" ::: "memory");   // own tile-i loads done
    } else {
      asm volatile("s_waitcnt vmcnt(0)" ::: "memory");
    }
    __builtin_amdgcn_s_barrier();                        // all waves' tile-i done
    __builtin_amdgcn_sched_barrier(0);

#pragma unroll
    for (int st = 0; st < 4; ++st) {
      short4v pf = *(const short4v*)&s_phi[cur][st * 256 + lane * 4];
      short4v g0 = *(const short4v*)&s_g[cur][st * 512 + lane * 4];
      short4v g1 = *(const short4v*)&s_g[cur][st * 512 + 256 + lane * 4];

      float4v zero4 = {0.f, 0.f, 0.f, 0.f};
      float4v s0 = __builtin_amdgcn_mfma_f32_16x16x16bf16_1k(pf, bt0, zero4, 0, 0, 0);
      float4v s1 = __builtin_amdgcn_mfma_f32_16x16x16bf16_1k(pf, bt1, zero4, 0, 0, 0);
      float4v s2 = __builtin_amdgcn_mfma_f32_16x16x16bf16_1k(pf, bt2, zero4, 0, 0, 0);
      float4v s3 = __builtin_amdgcn_mfma_f32_16x16x16bf16_1k(pf, bt3, zero4, 0, 0, 0);

      float p00 = __builtin_amdgcn_exp2f(s0[0]);
      float p01 = __builtin_amdgcn_exp2f(s0[1]);
      float p02 = __builtin_amdgcn_exp2f(s0[2]);
      float p03 = __builtin_amdgcn_exp2f(s0[3]);
      float p10 = __builtin_amdgcn_exp2f(s1[0]);
      float p11 = __builtin_amdgcn_exp2f(s1[1]);
      float p12 = __builtin_amdgcn_exp2f(s1[2]);
      float p13 = __builtin_amdgcn_exp2f(s1[3]);
      float p20 = __builtin_amdgcn_exp2f(s2[0]);
      float p21 = __builtin_amdgcn_exp2f(s2[1]);
      float p22 = __builtin_amdgcn_exp2f(s2[2]);
      float p23 = __builtin_amdgcn_exp2f(s2[3]);
      float p30 = __builtin_amdgcn_exp2f(s3[0]);
      float p31 = __builtin_amdgcn_exp2f(s3[1]);
      float p32 = __builtin_amdgcn_exp2f(s3[2]);
      float p33 = __builtin_amdgcn_exp2f(s3[3]);
      lsum0 += (p00 + p01) + (p02 + p03);
      lsum1 += (p10 + p11) + (p12 + p13);
      lsum2 += (p20 + p21) + (p22 + p23);
      lsum3 += (p30 + p31) + (p32 + p33);
      short4v pb0 = pack_bf16_trunc(p00, p01, p02, p03);
      short4v pb1 = pack_bf16_trunc(p10, p11, p12, p13);
      short4v pb2 = pack_bf16_trunc(p20, p21, p22, p23);
      short4v pb3 = pack_bf16_trunc(p30, p31, p32, p33);

      acc[0][0] = __builtin_amdgcn_mfma_f32_16x16x16bf16_1k(g0, pb0, acc[0][0], 0, 0, 0);
      acc[0][1] = __builtin_amdgcn_mfma_f32_16x16x16bf16_1k(g0, pb1, acc[0][1], 0, 0, 0);
      acc[0][2] = __builtin_amdgcn_mfma_f32_16x16x16bf16_1k(g0, pb2, acc[0][2], 0, 0, 0);
      acc[0][3] = __builtin_amdgcn_mfma_f32_16x16x16bf16_1k(g0, pb3, acc[0][3], 0, 0, 0);
      acc[1][0] = __builtin_amdgcn_mfma_f32_16x16x16bf16_1k(g1, pb0, acc[1][0], 0, 0, 0);
      acc[1][1] = __builtin_amdgcn_mfma_f32_16x16x16bf16_1k(g1, pb1, acc[1][1], 0, 0, 0);
      acc[1][2] = __builtin_amdgcn_mfma_f32_16x16x16bf16_1k(g1, pb2, acc[1][2], 0, 0, 0);
      acc[1][3] = __builtin_amdgcn_mfma_f32_16x16x16bf16_1k(g1, pb3, acc[1][3], 0, 0, 0);
    }

    // stage tile i+2 into buffer (cur+2)%3 — its last readers (tile i-1)
    // all passed this iteration's barrier.
    if (i + 2 < T) {
      int bb = (cur + 2 >= 3) ? cur - 1 : cur + 2;
      STAGE(t0 + i + 2, bb);
    }
    cur = (cur == 2) ? 0 : cur + 1;
  }
#undef STAGE

  lsum0 += __shfl_xor(lsum0, 16, 64);
  lsum0 += __shfl_xor(lsum0, 32, 64);
  lsum1 += __shfl_xor(lsum1, 16, 64);
  lsum1 += __shfl_xor(lsum1, 32, 64);
  lsum2 += __shfl_xor(lsum2, 16, 64);
  lsum2 += __shfl_xor(lsum2, 32, 64);
  lsum3 += __shfl_xor(lsum3, 16, 64);
  lsum3 += __shfl_xor(lsum3, 32, 64);

  size_t rowb = (size_t)(b * KS + ks) * QT64 + qt64;
  float myl = (l4 == 0) ? lsum0 : (l4 == 1) ? lsum1 : (l4 == 2) ? lsum2 : lsum3;
  lbuf[rowb * 64 + lane] = myl;   // entry q = l4*16+col

  size_t obase = rowb * 8 * 64 + lane;
#pragma unroll
  for (int h = 0; h < 2; ++h)
#pragma unroll
    for (int j = 0; j < 4; ++j)
      opart[obase + (size_t)(h * 4 + j) * 64] = pack_bf16x4_u2(acc[h][j]);
}

// ---------------------------------------------------------------------------
// Pass 2: combine bf16 partials, normalize, w_o epilogue MFMA, gamma, residual.
// Wave handles 32 queries. Grid (NPTS/128, NB).
// ---------------------------------------------------------------------------
template <int KS>
__global__ __launch_bounds__(256) void attn_combine(
    const float* __restrict__ x, const float* __restrict__ w_o,
    const float* __restrict__ gamma_p,
    const uint2* __restrict__ opart,
    const float* __restrict__ lbuf,
    float* __restrict__ out) {
  int tid = threadIdx.x;
  int wid = tid >> 6, lane = tid & 63;
  int l4 = lane >> 4, col = lane & 15;
  int b = blockIdx.y;
  int qt32 = blockIdx.x * 4 + wid;
  int qb = qt32 * 32;
  int qt64 = qt32 >> 1, hf = qt32 & 1;

  float gamma = gamma_p[0];

  short4v wo[4][2];
#pragma unroll
  for (int cot = 0; cot < 4; ++cot)
#pragma unroll
    for (int ksw = 0; ksw < 2; ++ksw) {
      const float* wp = w_o + (cot * 16 + col) * 32 + ksw * 16 + l4 * 4;
      wo[cot][ksw] = pack_bf16_rne(wp[0] * gamma, wp[1] * gamma,
                                   wp[2] * gamma, wp[3] * gamma);
    }

  float4v a0 = {0.f, 0.f, 0.f, 0.f}, a1 = a0, a2 = a0, a3 = a0;
  float ls0 = 0.f, ls1 = 0.f;
#pragma unroll
  for (int ks = 0; ks < KS; ++ks) {
    size_t rowb = (size_t)(b * KS + ks) * QT64 + qt64;
    size_t ob = (rowb * 8 + hf * 2) * 64 + lane;
    unpack_bf16x4_add(opart[ob + 0 * 64], &a0);   // h=0, qtile hf*2+0
    unpack_bf16x4_add(opart[ob + 1 * 64], &a1);   // h=0, qtile hf*2+1
    unpack_bf16x4_add(opart[ob + 4 * 64], &a2);   // h=1, qtile hf*2+0
    unpack_bf16x4_add(opart[ob + 5 * 64], &a3);   // h=1, qtile hf*2+1
    const float* lb = lbuf + rowb * 64 + hf * 32;
    ls0 += lb[col];
    ls1 += lb[col + 16];
  }
  float li0 = 1.0f / ls0;
  float li1 = 1.0f / ls1;

  short4v onb00 = pack_bf16_rne(a0[0] * li0, a0[1] * li0, a0[2] * li0, a0[3] * li0);
  short4v onb01 = pack_bf16_rne(a1[0] * li1, a1[1] * li1, a1[2] * li1, a1[3] * li1);
  short4v onb10 = pack_bf16_rne(a2[0] * li0, a2[1] * li0, a2[2] * li0, a2[3] * li0);
  short4v onb11 = pack_bf16_rne(a3[0] * li1, a3[1] * li1, a3[2] * li1, a3[3] * li1);

  float4v zero4 = {0.f, 0.f, 0.f, 0.f};
#pragma unroll
  for (int cot = 0; cot < 4; ++cot) {
#pragma unroll
    for (int nt = 0; nt < 2; ++nt) {
      short4v bfrag0 = nt ? onb01 : onb00;
      short4v bfrag1 = nt ? onb11 : onb10;
      float4v d = __builtin_amdgcn_mfma_f32_16x16x16bf16_1k(wo[cot][0], bfrag0, zero4, 0, 0, 0);
      d = __builtin_amdgcn_mfma_f32_16x16x16bf16_1k(wo[cot][1], bfrag1, d, 0, 0, 0);
      int n = qb + nt * 16 + col;
      size_t base = (size_t)(b * C_IN + cot * 16 + l4 * 4) * NPTS + n;
      const float* xp = x + base;
      float* op = out + base;
#pragma unroll
      for (int e = 0; e < 4; ++e) {
        op[(size_t)e * NPTS] = d[e] + xp[(size_t)e * NPTS];
      }
    }
  }
}

// ---------------------------------------------------------------------------
// Fallback single-pass attention (r5-proven) for small ws_size.
// ---------------------------------------------------------------------------
__global__ __launch_bounds__(256) void attn_mfma(
    const float* __restrict__ x, const float* __restrict__ w_o,
    const float* __restrict__ gamma_p,
    const unsigned short* __restrict__ theta_pad,
    const unsigned short* __restrict__ phi_f,
    const unsigned short* __restrict__ g_f,
    float* __restrict__ out) {
  __shared__ unsigned short s_phi[2][KT * 16];
  __shared__ unsigned short s_g[2][(KT / 16) * 512];

  int tid = threadIdx.x;
  int wid = tid >> 6, lane = tid & 63;
  int l4 = lane >> 4, col = lane & 15;
  int b = blockIdx.y;
  int qb = blockIdx.x * 128 + wid * 32;

  float gamma = gamma_p[0];

  const unsigned short* tb = theta_pad + ((size_t)(b * NPTS + qb) << 4) + l4 * 4;
  short4v bt0 = *(const short4v*)(tb + (col << 4));
  short4v bt1 = *(const short4v*)(tb + ((16 + col) << 4));

  short4v wo[4][2];
#pragma unroll
  for (int cot = 0; cot < 4; ++cot)
#pragma unroll
    for (int ksw = 0; ksw < 2; ++ksw) {
      const float* wp = w_o + (cot * 16 + col) * 32 + ksw * 16 + l4 * 4;
      wo[cot][ksw] = pack_bf16_rne(wp[0] * gamma, wp[1] * gamma,
                                   wp[2] * gamma, wp[3] * gamma);
    }

  const unsigned short* phib = phi_f + (size_t)b * 256 * 256;
  const unsigned short* gb   = g_f + (size_t)b * 256 * 512;

  float4v acc00 = {0.f, 0.f, 0.f, 0.f}, acc01 = acc00, acc10 = acc00, acc11 = acc00;
  float lsum0 = 0.f, lsum1 = 0.f;

  gl_lds16(gb + 0 * 2048 + wid * 512 + lane * 8, &s_g[0][wid * 512]);
  if (wid < 2)
    gl_lds16(phib + 0 * 1024 + wid * 512 + lane * 8, &s_phi[0][wid * 512]);
  __syncthreads();

#pragma unroll 1
  for (int t = 0; t < NTILE; ++t) {
    int cur = t & 1;
    if (t + 1 < NTILE) {
      gl_lds16(gb + (size_t)(t + 1) * 2048 + wid * 512 + lane * 8,
               &s_g[cur ^ 1][wid * 512]);
      if (wid < 2)
        gl_lds16(phib + (size_t)(t + 1) * 1024 + wid * 512 + lane * 8,
                 &s_phi[cur ^ 1][wid * 512]);
    }
#pragma unroll
    for (int st = 0; st < 4; ++st) {
      short4v pf = *(const short4v*)&s_phi[cur][st * 256 + lane * 4];
      short4v g0 = *(const short4v*)&s_g[cur][st * 512 + lane * 4];
      short4v g1 = *(const short4v*)&s_g[cur][st * 512 + 256 + lane * 4];

      float4v zero4 = {0.f, 0.f, 0.f, 0.f};
      float4v s0 = __builtin_amdgcn_mfma_f32_16x16x16bf16_1k(pf, bt0, zero4, 0, 0, 0);
      float4v s1 = __builtin_amdgcn_mfma_f32_16x16x16bf16_1k(pf, bt1, zero4, 0, 0, 0);

      float p00 = __builtin_amdgcn_exp2f(s0[0]);
      float p01 = __builtin_amdgcn_exp2f(s0[1]);
      float p02 = __builtin_amdgcn_exp2f(s0[2]);
      float p03 = __builtin_amdgcn_exp2f(s0[3]);
      float p10 = __builtin_amdgcn_exp2f(s1[0]);
      float p11 = __builtin_amdgcn_exp2f(s1[1]);
      float p12 = __builtin_amdgcn_exp2f(s1[2]);
      float p13 = __builtin_amdgcn_exp2f(s1[3]);
      lsum0 += (p00 + p01) + (p02 + p03);
      lsum1 += (p10 + p11) + (p12 + p13);
      short4v pb0 = pack_bf16_trunc(p00, p01, p02, p03);
      short4v pb1 = pack_bf16_trunc(p10, p11, p12, p13);

      acc00 = __builtin_amdgcn_mfma_f32_16x16x16bf16_1k(g0, pb0, acc00, 0, 0, 0);
      acc01 = __builtin_amdgcn_mfma_f32_16x16x16bf16_1k(g0, pb1, acc01, 0, 0, 0);
      acc10 = __builtin_amdgcn_mfma_f32_16x16x16bf16_1k(g1, pb0, acc10, 0, 0, 0);
      acc11 = __builtin_amdgcn_mfma_f32_16x16x16bf16_1k(g1, pb1, acc11, 0, 0, 0);
    }
    __syncthreads();
  }

  lsum0 += __shfl_xor(lsum0, 16, 64);
  lsum0 += __shfl_xor(lsum0, 32, 64);
  lsum1 += __shfl_xor(lsum1, 16, 64);
  lsum1 += __shfl_xor(lsum1, 32, 64);
  float li0 = 1.0f / lsum0;
  float li1 = 1.0f / lsum1;

  short4v onb00 = pack_bf16_rne(acc00[0] * li0, acc00[1] * li0, acc00[2] * li0, acc00[3] * li0);
  short4v onb01 = pack_bf16_rne(acc01[0] * li1, acc01[1] * li1, acc01[2] * li1, acc01[3] * li1);
  short4v onb10 = pack_bf16_rne(acc10[0] * li0, acc10[1] * li0, acc10[2] * li0, acc10[3] * li0);
  short4v onb11 = pack_bf16_rne(acc11[0] * li1, acc11[1] * li1, acc11[2] * li1, acc11[3] * li1);

  float4v zero4 = {0.f, 0.f, 0.f, 0.f};
#pragma unroll
  for (int cot = 0; cot < 4; ++cot) {
#pragma unroll
    for (int nt = 0; nt < 2; ++nt) {
      short4v bfrag0 = nt ? onb01 : onb00;
      short4v bfrag1 = nt ? onb11 : onb10;
      float4v d = __builtin_amdgcn_mfma_f32_16x16x16bf16_1k(wo[cot][0], bfrag0, zero4, 0, 0, 0);
      d = __builtin_amdgcn_mfma_f32_16x16x16bf16_1k(wo[cot][1], bfrag1, d, 0, 0, 0);
      int n = qb + nt * 16 + col;
      size_t base = (size_t)(b * C_IN + cot * 16 + l4 * 4) * NPTS + n;
      const float* xp = x + base;
      float* op = out + base;
#pragma unroll
      for (int e = 0; e < 4; ++e) {
        op[(size_t)e * NPTS] = d[e] + xp[(size_t)e * NPTS];
      }
    }
  }
}

extern "C" void kernel_launch(void* const* d_in, const int* in_sizes, int n_in,
                              void* d_out, int out_size, void* d_ws, size_t ws_size,
                              hipStream_t stream) {
  const float* x       = (const float*)d_in[0];
  const float* w_theta = (const float*)d_in[1];
  const float* w_phi   = (const float*)d_in[2];
  const float* w_g     = (const float*)d_in[3];
  const float* w_o     = (const float*)d_in[4];
  const float* gamma   = (const float*)d_in[5];
  float* out = (float*)d_out;

  char* ws = (char*)d_ws;
  unsigned short* phi_f     = (unsigned short*)ws;  ws += (size_t)NB * 256 * 256 * 2;  // 256 KB
  unsigned short* g_f       = (unsigned short*)ws;  ws += (size_t)NB * 256 * 512 * 2;  // 512 KB
  unsigned short* theta_pad = (unsigned short*)ws;  ws += (size_t)NB * NPTS * 16 * 2;  // 2 MB
  size_t base_need = (size_t)(ws - (char*)d_ws);
  uint2* opart = (uint2*)ws;
  size_t opart4 = (size_t)NB * 4 * QT64 * 8 * 64 * sizeof(uint2);    // 16.8 MB
  size_t opart2 = (size_t)NB * 2 * QT64 * 8 * 64 * sizeof(uint2);    // 8.4 MB
  size_t lbuf4  = (size_t)NB * 4 * QT64 * 64 * sizeof(float);        // 1 MB
  size_t lbuf2  = (size_t)NB * 2 * QT64 * 64 * sizeof(float);
  size_t need4 = base_need + opart4 + lbuf4;
  size_t need2 = base_need + opart2 + lbuf2;

  prep_fused<<<dim3(576), dim3(256), 0, stream>>>(
      x, w_theta, w_phi, w_g, theta_pad, phi_f, g_f);

  if (ws_size >= need4) {
    float* lbuf = (float*)((char*)opart + opart4);
    attn_split64<4><<<dim3(NPTS / 256, NB * 4), dim3(256), 0, stream>>>(
        theta_pad, phi_f, g_f, opart, lbuf);
    attn_combine<4><<<dim3(NPTS / 128, NB), dim3(256), 0, stream>>>(
        x, w_o, gamma, opart, lbuf, out);
  } else if (ws_size >= need2) {
    float* lbuf = (float*)((char*)opart + opart2);
    attn_split64<2><<<dim3(NPTS / 256, NB * 2), dim3(256), 0, stream>>>(
        theta_pad, phi_f, g_f, opart, lbuf);
    attn_combine<2><<<dim3(NPTS / 128, NB), dim3(256), 0, stream>>>(
        x, w_o, gamma, opart, lbuf, out);
  } else if (ws_size >= base_need) {
    attn_mfma<<<dim3(NPTS / 128, NB), dim3(256), 0, stream>>>(
        x, w_o, gamma, theta_pad, phi_f, g_f, out);
  }
}